// Round 1
// 2944.644 us; speedup vs baseline: 1.2860x; 1.2860x over previous
//
// FineTuneMolFormer — Round 5: kvsum rebuilt (split partials, no atomics/LDS/
// barriers; partial slabs alias the dead Xb region of d_out), phi -> MFMA
// (K=64,N=32 GEMM per head, omegaT in padded LDS), LN via wave shfl reduce.
// ws: 6 W^T (28.3) + Xf fp32 (100.7) + Ab (50.3) + KV/KSUM/ZR (3.2) ~= 183 MB.
// d_out: [Xb bf16 | KVp/KSUMp partials][PHQ|PHK / y-buf]; final LN writes last.
#include <hip/hip_runtime.h>
#include <math.h>

#define Bsz 16
#define Lseq 2048
#define Dm 768
#define Hn 12
#define HDim 64
#define Fdim 32
#define NLayers 4
#define NTOK (Bsz * Lseq)
#define NSPLIT 16

typedef __bf16 bf16;
typedef bf16 bf16x8 __attribute__((ext_vector_type(8)));
typedef float f32x4 __attribute__((ext_vector_type(4)));

#define AS1(p) ((__attribute__((address_space(1))) void*)(uintptr_t)(p))
#define AS3(p) ((__attribute__((address_space(3))) void*)(p))

// ---------------------------------------------------------------------------
// Weight convert+transpose: W[l][k][n] fp32 -> Wt[l][n][k] bf16. 32x32 tiles.
// ---------------------------------------------------------------------------
__global__ __launch_bounds__(256) void wconv_kernel(const float* __restrict__ W,
                                                    bf16* __restrict__ Wt) {
  __shared__ float t[32][33];
  int l = blockIdx.z;
  int kb = blockIdx.y * 32, nb = blockIdx.x * 32;
  const float* Wl = W + (size_t)l * Dm * Dm;
  bf16* Wtl = Wt + (size_t)l * Dm * Dm;
  int tx = threadIdx.x, ty = threadIdx.y;  // 32 x 8
#pragma unroll
  for (int i = 0; i < 32; i += 8)
    t[ty + i][tx] = Wl[(size_t)(kb + ty + i) * Dm + nb + tx];
  __syncthreads();
#pragma unroll
  for (int i = 0; i < 32; i += 8)
    Wtl[(size_t)(nb + ty + i) * Dm + kb + tx] = (bf16)t[tx][ty + i];
}

// ---------------------------------------------------------------------------
// bf16 MFMA GEMM: C[M][N=768] = A[M][K=768] @ Wt[N][K]^T + bias
// (+gelu if act, +in-register rotary if rot). 128x128 tile, BK=32, 4 waves.
// ---------------------------------------------------------------------------
__global__ __launch_bounds__(256) void gemm_mfma_kernel(
    const bf16* __restrict__ A, const bf16* __restrict__ Wt,
    const float* __restrict__ bias, bf16* __restrict__ C, int act, int rot) {
  const int K = Dm, N = Dm;
  __shared__ bf16 As[128 * 32];
  __shared__ bf16 Bs[128 * 32];
  const int tid = threadIdx.x;
  const int lane = tid & 63;
  const int wave = tid >> 6;
  const int wr = (wave >> 1) << 6;
  const int wc = (wave & 1) << 6;
  const int m0 = blockIdx.y << 7;
  const int n0 = blockIdx.x << 7;
  const int c0 = tid, c1 = tid + 256;
  const bf16* a0 = A + (size_t)(m0 + (c0 >> 2)) * K + ((c0 & 3) << 3);
  const bf16* a1 = A + (size_t)(m0 + (c1 >> 2)) * K + ((c1 & 3) << 3);
  const bf16* b0 = Wt + (size_t)(n0 + (c0 >> 2)) * K + ((c0 & 3) << 3);
  const bf16* b1 = Wt + (size_t)(n0 + (c1 >> 2)) * K + ((c1 & 3) << 3);
  bf16* const As0 = As + c0 * 8;
  bf16* const As1 = As + c1 * 8;
  bf16* const Bs0 = Bs + c0 * 8;
  bf16* const Bs1 = Bs + c1 * 8;

  const int la = lane & 15, qd = lane >> 4;
  const int aoff = (wr + la) * 32 + qd * 8;
  const int boff = (wc + la) * 32 + qd * 8;

  f32x4 acc[4][4] = {};

  for (int k0 = 0; k0 < K; k0 += 32) {
    __builtin_amdgcn_global_load_lds(AS1(a0 + k0), AS3(As0), 16, 0, 0);
    __builtin_amdgcn_global_load_lds(AS1(a1 + k0), AS3(As1), 16, 0, 0);
    __builtin_amdgcn_global_load_lds(AS1(b0 + k0), AS3(Bs0), 16, 0, 0);
    __builtin_amdgcn_global_load_lds(AS1(b1 + k0), AS3(Bs1), 16, 0, 0);
    __syncthreads();
    bf16x8 af[4], bfr[4];
#pragma unroll
    for (int i = 0; i < 4; ++i) af[i] = *(const bf16x8*)(As + aoff + i * 512);
#pragma unroll
    for (int j = 0; j < 4; ++j) bfr[j] = *(const bf16x8*)(Bs + boff + j * 512);
#pragma unroll
    for (int i = 0; i < 4; ++i)
#pragma unroll
      for (int j = 0; j < 4; ++j)
        acc[i][j] = __builtin_amdgcn_mfma_f32_16x16x32_bf16(af[i], bfr[j],
                                                            acc[i][j], 0, 0, 0);
    __syncthreads();
  }

  // C/D layout: col = lane&15, row = (lane>>4)*4 + reg
  if (!rot) {
#pragma unroll
    for (int i = 0; i < 4; ++i) {
      int rbase = m0 + wr + i * 16 + qd * 4;
#pragma unroll
      for (int j = 0; j < 4; ++j) {
        int col = n0 + wc + j * 16 + la;
        float bc = bias[col];
#pragma unroll
        for (int r = 0; r < 4; ++r) {
          float v = acc[i][j][r] + bc;
          if (act) v = 0.5f * v * (1.0f + erff(v * 0.70710678118654752f));
          C[(size_t)(rbase + r) * N + col] = (bf16)v;
        }
      }
    }
  } else {
    // Wave's 64-col span == one head (n0+wc is 64-aligned). Rotary pair
    // (d, d+32) lives in acc[i][jj] / acc[i][jj+2] of the SAME lane.
#pragma unroll
    for (int i = 0; i < 4; ++i) {
      int rbase = m0 + wr + i * 16 + qd * 4;
#pragma unroll
      for (int jj = 0; jj < 2; ++jj) {
        int d = jj * 16 + la;  // 0..31 within head
        int col1 = n0 + wc + d;
        int col2 = col1 + 32;
        float b1c = bias[col1], b2c = bias[col2];
        float inv = expf(-(float)d * (9.210340371976184f / 32.0f));
#pragma unroll
        for (int r = 0; r < 4; ++r) {
          int row = rbase + r;
          int l = row & (Lseq - 1);
          float fr = (float)l * inv;
          float s, c;
          sincosf(fr, &s, &c);
          float x1 = acc[i][jj][r] + b1c;
          float x2 = acc[i][jj + 2][r] + b2c;
          C[(size_t)row * N + col1] = (bf16)(x1 * c - x2 * s);
          C[(size_t)row * N + col2] = (bf16)(x2 * c + x1 * s);
        }
      }
    }
  }
}

// ---------------------------------------------------------------------------
// Embedding gather -> Xf fp32 + Xb bf16
// ---------------------------------------------------------------------------
__global__ __launch_bounds__(256) void embed_kernel(
    const int* __restrict__ idx, const float* __restrict__ emb,
    float* __restrict__ Xf, bf16* __restrict__ Xb) {
  int o = blockIdx.x * 256 + threadIdx.x;
  int t = o / Dm, d = o - t * Dm;
  float v = emb[(size_t)idx[t] * Dm + d];
  Xf[o] = v;
  Xb[o] = (bf16)v;
}

// ---------------------------------------------------------------------------
// phi = relu(q @ omega) [* mask] via MFMA. Per head: [NTOK x 64] @ [64 x 32].
// Block = (256-token chunk, h). omegaT staged bf16 in LDS [32 f][72 pad].
// Wave = 64 tokens; K=64 -> 2 mfma k-steps; A-frags read direct from global.
// ---------------------------------------------------------------------------
__global__ __launch_bounds__(256) void phi_mfma_kernel(
    const bf16* __restrict__ qk, const float* __restrict__ omega,
    const int* __restrict__ mask, bf16* __restrict__ ph) {
  __shared__ bf16 omT[32][72];
  int tid = threadIdx.x;
  for (int i = tid; i < HDim * Fdim; i += 256) {
    int d = i >> 5, f = i & 31;
    omT[f][d] = (bf16)omega[i];
  }
  __syncthreads();
  const int h = blockIdx.y;
  const int lane = tid & 63, wave = tid >> 6;
  const int la = lane & 15, qd = lane >> 4;
  const int t0 = blockIdx.x * 256 + wave * 64;
  const bf16* qbase = qk + (size_t)t0 * Dm + h * HDim;

  bf16x8 bfr[2][2];
#pragma unroll
  for (int j = 0; j < 2; ++j)
#pragma unroll
    for (int ks = 0; ks < 2; ++ks)
      bfr[j][ks] = *(const bf16x8*)(&omT[j * 16 + la][ks * 32 + qd * 8]);

  f32x4 acc[4][2] = {};
#pragma unroll
  for (int ks = 0; ks < 2; ++ks) {
    bf16x8 af[4];
#pragma unroll
    for (int i = 0; i < 4; ++i)
      af[i] = *(const bf16x8*)(qbase + (size_t)(i * 16 + la) * Dm + ks * 32 +
                               qd * 8);
#pragma unroll
    for (int i = 0; i < 4; ++i)
#pragma unroll
      for (int j = 0; j < 2; ++j)
        acc[i][j] = __builtin_amdgcn_mfma_f32_16x16x32_bf16(af[i], bfr[j][ks],
                                                            acc[i][j], 0, 0, 0);
  }
  // C/D: col f = j*16+la, row t = t0 + i*16 + qd*4 + r
#pragma unroll
  for (int i = 0; i < 4; ++i) {
#pragma unroll
    for (int r = 0; r < 4; ++r) {
      int row = t0 + i * 16 + qd * 4 + r;
      float mm = mask ? (float)mask[row] : 1.0f;
#pragma unroll
      for (int j = 0; j < 2; ++j) {
        float val = fmaxf(acc[i][j][r], 0.0f) * mm;
        ph[(size_t)row * (Hn * Fdim) + h * Fdim + j * 16 + la] = (bf16)val;
      }
    }
  }
}

// ---------------------------------------------------------------------------
// kvsum split-L, no atomics: grid (Bsz*Hn, NSPLIT). Each thread owns
// (f, d0..d0+7) with fp32 register accum; phk scalar load is a wave
// broadcast, v load is bf16x8. Writes per-split partial slabs.
// ---------------------------------------------------------------------------
__global__ __launch_bounds__(256) void kvsum_kernel(
    const bf16* __restrict__ phk, const bf16* __restrict__ v,
    float* __restrict__ kvp, float* __restrict__ ksump) {
  const int bh = blockIdx.x;
  const int b = bh / Hn, h = bh - b * Hn;
  const int s = blockIdx.y;
  const int tid = threadIdx.x;
  const int f = tid >> 3, d0 = (tid & 7) << 3;
  const int lbeg = s * (Lseq / NSPLIT);
  const bf16* pp =
      phk + (size_t)(b * Lseq + lbeg) * (Hn * Fdim) + h * Fdim + f;
  const bf16* vp = v + (size_t)(b * Lseq + lbeg) * Dm + h * HDim + d0;
  float acc[8] = {};
  float ks = 0.0f;
#pragma unroll 4
  for (int l = 0; l < Lseq / NSPLIT; ++l) {
    float p = (float)pp[(size_t)l * (Hn * Fdim)];
    bf16x8 vv = *(const bf16x8*)(vp + (size_t)l * Dm);
    ks += p;
#pragma unroll
    for (int q = 0; q < 8; ++q) acc[q] = fmaf(p, (float)vv[q], acc[q]);
  }
  // layout [s][bh][f][d]: elem offset f*64 + d0 == tid*8
  float* o = kvp + (size_t)(s * (Bsz * Hn) + bh) * (Fdim * HDim) + tid * 8;
  f32x4 lo = {acc[0], acc[1], acc[2], acc[3]};
  f32x4 hi = {acc[4], acc[5], acc[6], acc[7]};
  *(f32x4*)o = lo;
  *(f32x4*)(o + 4) = hi;
  if ((tid & 7) == 0)
    ksump[(size_t)(s * (Bsz * Hn) + bh) * Fdim + f] = ks;
}

// ---------------------------------------------------------------------------
// Reduce NSPLIT partial slabs -> KV, KSUM. Fully overwrites (no zero-init).
// ---------------------------------------------------------------------------
__global__ __launch_bounds__(256) void kvreduce_kernel(
    const float* __restrict__ kvp, const float* __restrict__ ksump,
    float* __restrict__ kv, float* __restrict__ ksum) {
  const int idx = blockIdx.x * 256 + threadIdx.x;  // < 192*2048
  float a = 0.0f;
#pragma unroll
  for (int s = 0; s < NSPLIT; ++s)
    a += kvp[(size_t)s * (Bsz * Hn * Fdim * HDim) + idx];
  kv[idx] = a;
  if (idx < Bsz * Hn * Fdim) {
    float k2 = 0.0f;
#pragma unroll
    for (int s = 0; s < NSPLIT; ++s)
      k2 += ksump[(size_t)s * (Bsz * Hn * Fdim) + idx];
    ksum[idx] = k2;
  }
}

// ---------------------------------------------------------------------------
// zrecip[t,h] = 1 / (sum_f phq[t,h,f]*ksum[b,h,f] + 1e-6)
// ---------------------------------------------------------------------------
__global__ __launch_bounds__(256) void zden_kernel(
    const bf16* __restrict__ phq, const float* __restrict__ ksum,
    float* __restrict__ zr) {
  int idx = blockIdx.x * 256 + threadIdx.x;  // < NTOK*Hn
  int h = idx % Hn;
  int b = idx / (Lseq * Hn);
  const bf16* pq = phq + (size_t)idx * Fdim;
  const float* ks = ksum + ((size_t)b * Hn + h) * Fdim;
  float acc = 0.0f;
#pragma unroll
  for (int f = 0; f < Fdim; ++f) acc = fmaf((float)pq[f], ks[f], acc);
  zr[idx] = 1.0f / (acc + 1e-6f);
}

// ---------------------------------------------------------------------------
// Attention combine via MFMA: out[t,h,:] = (phq[t,h,:] @ kv[b,h]) * zr[t,h].
// Block = (256-token chunk, bh). kv -> bf16 LDS [d][f] (stride 40, 2-way ok).
// K=32 == one mfma_f32_16x16x32_bf16. Wave = 64 tokens x 64 d.
// ---------------------------------------------------------------------------
__global__ __launch_bounds__(256) void attn_mfma_kernel(
    const bf16* __restrict__ phq, const float* __restrict__ kv,
    const float* __restrict__ zr, bf16* __restrict__ out) {
  __shared__ bf16 kvb[64 * 40];
  int bh = blockIdx.y;
  int b = bh / Hn, h = bh - b * Hn;
  int tid = threadIdx.x, lane = tid & 63, wave = tid >> 6;
  {  // transpose-load kv[f][d] fp32 -> kvb[d][f] bf16
    int d = tid >> 2, f0 = (tid & 3) << 3;
    const float* src = kv + ((size_t)bh * Fdim + f0) * HDim + d;
    bf16x8 tmp;
#pragma unroll
    for (int q = 0; q < 8; ++q) tmp[q] = (bf16)src[(size_t)q * HDim];
    *(bf16x8*)(kvb + d * 40 + f0) = tmp;
  }
  __syncthreads();
  const int la = lane & 15, qd = lane >> 4;
  const int t0 = b * Lseq + blockIdx.x * 256 + wave * 64;
  bf16x8 bfr[4];
#pragma unroll
  for (int jt = 0; jt < 4; ++jt)
    bfr[jt] = *(const bf16x8*)(kvb + (jt * 16 + la) * 40 + qd * 8);
  bf16x8 af[4];
#pragma unroll
  for (int i = 0; i < 4; ++i)
    af[i] = *(const bf16x8*)(phq +
                             ((size_t)(t0 + i * 16 + la) * Hn + h) * Fdim +
                             qd * 8);
  f32x4 acc[4][4] = {};
#pragma unroll
  for (int i = 0; i < 4; ++i)
#pragma unroll
    for (int jt = 0; jt < 4; ++jt)
      acc[i][jt] = __builtin_amdgcn_mfma_f32_16x16x32_bf16(af[i], bfr[jt],
                                                           acc[i][jt], 0, 0, 0);
#pragma unroll
  for (int i = 0; i < 4; ++i) {
    int rbase = t0 + i * 16 + qd * 4;
#pragma unroll
    for (int r = 0; r < 4; ++r) {
      float z = zr[(size_t)(rbase + r) * Hn + h];
#pragma unroll
      for (int jt = 0; jt < 4; ++jt)
        out[(size_t)(rbase + r) * Dm + h * HDim + jt * 16 + la] =
            (bf16)(acc[i][jt][r] * z);
    }
  }
}

// ---------------------------------------------------------------------------
// Fused residual + LayerNorm: h = Xf + y; writes Xf (fp32) and Xb (bf16).
// Wave shfl reduce; 2 barriers total.
// ---------------------------------------------------------------------------
__global__ __launch_bounds__(256) void ln_residual_kernel(
    const bf16* __restrict__ y, const float* __restrict__ xres,
    const float* __restrict__ g, const float* __restrict__ be,
    float* __restrict__ xf_out, bf16* __restrict__ xb_out) {
  __shared__ float red[8];
  int t = blockIdx.x, tid = threadIdx.x;
  int lane = tid & 63, wave = tid >> 6;
  const bf16* yr = y + (size_t)t * Dm;
  const float* xr = xres + (size_t)t * Dm;
  float v0 = xr[tid] + (float)yr[tid];
  float v1 = xr[tid + 256] + (float)yr[tid + 256];
  float v2 = xr[tid + 512] + (float)yr[tid + 512];
  float s = v0 + v1 + v2;
#pragma unroll
  for (int off = 32; off > 0; off >>= 1) s += __shfl_xor(s, off, 64);
  if (lane == 0) red[wave] = s;
  __syncthreads();
  float mu = (red[0] + red[1] + red[2] + red[3]) * (1.0f / 768.0f);
  float d0 = v0 - mu, d1 = v1 - mu, d2 = v2 - mu;
  float s2 = d0 * d0 + d1 * d1 + d2 * d2;
#pragma unroll
  for (int off = 32; off > 0; off >>= 1) s2 += __shfl_xor(s2, off, 64);
  if (lane == 0) red[4 + wave] = s2;
  __syncthreads();
  float rs =
      rsqrtf((red[4] + red[5] + red[6] + red[7]) * (1.0f / 768.0f) + 1e-5f);
  float o0 = d0 * rs * g[tid] + be[tid];
  float o1 = d1 * rs * g[tid + 256] + be[tid + 256];
  float o2 = d2 * rs * g[tid + 512] + be[tid + 512];
  float* xo = xf_out + (size_t)t * Dm;
  bf16* bo = xb_out + (size_t)t * Dm;
  xo[tid] = o0;
  xo[tid + 256] = o1;
  xo[tid + 512] = o2;
  bo[tid] = (bf16)o0;
  bo[tid + 256] = (bf16)o1;
  bo[tid + 512] = (bf16)o2;
}

// ---------------------------------------------------------------------------
// Final LayerNorm: fp32 in -> fp32 out (d_out). Wave shfl reduce.
// ---------------------------------------------------------------------------
__global__ __launch_bounds__(256) void ln_final_kernel(
    const float* __restrict__ x, const float* __restrict__ g,
    const float* __restrict__ be, float* __restrict__ out) {
  __shared__ float red[8];
  int t = blockIdx.x, tid = threadIdx.x;
  int lane = tid & 63, wave = tid >> 6;
  const float* xr = x + (size_t)t * Dm;
  float v0 = xr[tid], v1 = xr[tid + 256], v2 = xr[tid + 512];
  float s = v0 + v1 + v2;
#pragma unroll
  for (int off = 32; off > 0; off >>= 1) s += __shfl_xor(s, off, 64);
  if (lane == 0) red[wave] = s;
  __syncthreads();
  float mu = (red[0] + red[1] + red[2] + red[3]) * (1.0f / 768.0f);
  float d0 = v0 - mu, d1 = v1 - mu, d2 = v2 - mu;
  float s2 = d0 * d0 + d1 * d1 + d2 * d2;
#pragma unroll
  for (int off = 32; off > 0; off >>= 1) s2 += __shfl_xor(s2, off, 64);
  if (lane == 0) red[4 + wave] = s2;
  __syncthreads();
  float rs =
      rsqrtf((red[4] + red[5] + red[6] + red[7]) * (1.0f / 768.0f) + 1e-5f);
  float* outr = out + (size_t)t * Dm;
  outr[tid] = d0 * rs * g[tid] + be[tid];
  outr[tid + 256] = d1 * rs * g[tid + 256] + be[tid + 256];
  outr[tid + 512] = d2 * rs * g[tid + 512] + be[tid + 512];
}

// ---------------------------------------------------------------------------
extern "C" void kernel_launch(void* const* d_in, const int* in_sizes, int n_in,
                              void* d_out, int out_size, void* d_ws,
                              size_t ws_size, hipStream_t stream) {
  const int* idx = (const int*)d_in[0];
  const int* mask = (const int*)d_in[1];
  const float* tok_emb = (const float*)d_in[2];
  const float* Wq = (const float*)d_in[3];
  const float* bq = (const float*)d_in[4];
  const float* Wk = (const float*)d_in[5];
  const float* bk = (const float*)d_in[6];
  const float* Wv = (const float*)d_in[7];
  const float* bv = (const float*)d_in[8];
  const float* Wo = (const float*)d_in[9];
  const float* bo = (const float*)d_in[10];
  const float* omega = (const float*)d_in[11];
  const float* W1 = (const float*)d_in[12];
  const float* b1 = (const float*)d_in[13];
  const float* W2 = (const float*)d_in[14];
  const float* b2 = (const float*)d_in[15];
  const float* g1 = (const float*)d_in[16];
  const float* be1 = (const float*)d_in[17];
  const float* g2 = (const float*)d_in[18];
  const float* be2 = (const float*)d_in[19];
  const float* gf = (const float*)d_in[20];
  const float* bf = (const float*)d_in[21];

  const size_t TD = (size_t)NTOK * Dm;
  const size_t WSZ = (size_t)NLayers * Dm * Dm;
  bf16* wsb = (bf16*)d_ws;
  bf16* WqT = wsb;
  bf16* WkT = WqT + WSZ;
  bf16* WvT = WkT + WSZ;
  bf16* WoT = WvT + WSZ;
  bf16* W1T = WoT + WSZ;
  bf16* W2T = W1T + WSZ;
  float* Xf = (float*)(wsb + 6 * WSZ);  // fp32 residual stream
  bf16* Ab = (bf16*)(Xf + TD);          // q/k/v -> attn-out -> ffn hidden
  float* KV = (float*)(Ab + TD);
  float* KSUM = KV + (size_t)Bsz * Hn * Fdim * HDim;
  float* ZR = KSUM + (size_t)Bsz * Hn * Fdim;  // zrecip[t,h], 1.5 MB
  // d_out aliasing: [Xb bf16 (TD)][PHQ (TD/2) | PHK (TD/2) -> y-buf (TD)]
  // KVp/KSUMp partials (25.6 MB) alias the Xb region, which is dead between
  // the V-GEMM (last read) and ln_residual (next write).
  bf16* Xb = (bf16*)d_out;
  bf16* PHQ = Xb + TD;
  bf16* PHK = PHQ + (size_t)NTOK * Hn * Fdim;
  bf16* Yb = PHQ;
  float* KVP = (float*)d_out;
  float* KSUMP = KVP + (size_t)NSPLIT * Bsz * Hn * Fdim * HDim;

  dim3 wg(Dm / 32, Dm / 32, NLayers), wb(32, 8);
  wconv_kernel<<<wg, wb, 0, stream>>>(Wq, WqT);
  wconv_kernel<<<wg, wb, 0, stream>>>(Wk, WkT);
  wconv_kernel<<<wg, wb, 0, stream>>>(Wv, WvT);
  wconv_kernel<<<wg, wb, 0, stream>>>(Wo, WoT);
  wconv_kernel<<<wg, wb, 0, stream>>>(W1, W1T);
  wconv_kernel<<<wg, wb, 0, stream>>>(W2, W2T);

  dim3 gg(Dm / 128, NTOK / 128), gb(256);
  dim3 kvg(Bsz * Hn, NSPLIT);
  dim3 ag(Lseq / 256, Bsz * Hn);
  dim3 pg(NTOK / 256, Hn);
  const int elem_grid = (NTOK * Dm) / 256;
  const int zden_grid = (NTOK * Hn) / 256;
  const int kvr_grid = (Bsz * Hn * Fdim * HDim) / 256;

  embed_kernel<<<elem_grid, 256, 0, stream>>>(idx, tok_emb, Xf, Xb);

  for (int i = 0; i < NLayers; ++i) {
    const size_t wo = (size_t)i * Dm * Dm;
    const size_t bo_ = (size_t)i * Dm;
    const float* omi = omega + (size_t)i * HDim * Fdim;

    // Q (rotary fused) -> Ab -> PHQ
    gemm_mfma_kernel<<<gg, gb, 0, stream>>>(Xb, WqT + wo, bq + bo_, Ab, 0, 1);
    phi_mfma_kernel<<<pg, 256, 0, stream>>>(Ab, omi, nullptr, PHQ);
    // K (rotary fused) -> Ab -> PHK (masked)
    gemm_mfma_kernel<<<gg, gb, 0, stream>>>(Xb, WkT + wo, bk + bo_, Ab, 0, 1);
    phi_mfma_kernel<<<pg, 256, 0, stream>>>(Ab, omi, mask, PHK);
    // V -> Ab; kv state (partials over dead Xb); reduce; zden; attn -> Ab
    gemm_mfma_kernel<<<gg, gb, 0, stream>>>(Xb, WvT + wo, bv + bo_, Ab, 0, 0);
    kvsum_kernel<<<kvg, 256, 0, stream>>>(PHK, Ab, KVP, KSUMP);
    kvreduce_kernel<<<kvr_grid, 256, 0, stream>>>(KVP, KSUMP, KV, KSUM);
    zden_kernel<<<zden_grid, 256, 0, stream>>>(PHQ, KSUM, ZR);
    attn_mfma_kernel<<<ag, 256, 0, stream>>>(PHQ, KV, ZR, Ab);
    // y = attn@Wo + bo -> Yb; LN1(Xf + y) -> Xf, Xb
    gemm_mfma_kernel<<<gg, gb, 0, stream>>>(Ab, WoT + wo, bo + bo_, Yb, 0, 0);
    ln_residual_kernel<<<NTOK, 256, 0, stream>>>(Yb, Xf, g1 + bo_, be1 + bo_,
                                                 Xf, Xb);
    // gelu(Xb@W1+b1) -> Ab; y = Ab@W2+b2 -> Yb; LN2(Xf + y) -> Xf, Xb
    gemm_mfma_kernel<<<gg, gb, 0, stream>>>(Xb, W1T + wo, b1 + bo_, Ab, 1, 0);
    gemm_mfma_kernel<<<gg, gb, 0, stream>>>(Ab, W2T + wo, b2 + bo_, Yb, 0, 0);
    ln_residual_kernel<<<NTOK, 256, 0, stream>>>(Yb, Xf, g2 + bo_, be2 + bo_,
                                                 Xf, Xb);
  }
  ln_final_kernel<<<NTOK, 256, 0, stream>>>(Xf, gf, bf, (float*)d_out);
}

// Round 2
// 2916.334 us; speedup vs baseline: 1.2984x; 1.0097x over previous
//
// FineTuneMolFormer — Round 6: GEMM gets (a) double-buffered LDS with counted
// s_waitcnt vmcnt(4) + raw s_barrier (T3/T4: next tile's global_load_lds stay
// in flight across the barrier), (b) XCD-bijective block swizzle so the 6
// N-tiles sharing an A-band land on one XCD's L2 (1536 = 8*192, 192%6==0).
// Everything else unchanged from Round 5.
// ws: 6 W^T (28.3) + Xf fp32 (100.7) + Ab (50.3) + KV/KSUM/ZR (3.2) ~= 183 MB.
// d_out: [Xb bf16 | KVp/KSUMp partials][PHQ|PHK / y-buf]; final LN writes last.
#include <hip/hip_runtime.h>
#include <math.h>

#define Bsz 16
#define Lseq 2048
#define Dm 768
#define Hn 12
#define HDim 64
#define Fdim 32
#define NLayers 4
#define NTOK (Bsz * Lseq)
#define NSPLIT 16

typedef __bf16 bf16;
typedef bf16 bf16x8 __attribute__((ext_vector_type(8)));
typedef float f32x4 __attribute__((ext_vector_type(4)));

#define AS1(p) ((__attribute__((address_space(1))) void*)(uintptr_t)(p))
#define AS3(p) ((__attribute__((address_space(3))) void*)(p))

// ---------------------------------------------------------------------------
// Weight convert+transpose: W[l][k][n] fp32 -> Wt[l][n][k] bf16. 32x32 tiles.
// ---------------------------------------------------------------------------
__global__ __launch_bounds__(256) void wconv_kernel(const float* __restrict__ W,
                                                    bf16* __restrict__ Wt) {
  __shared__ float t[32][33];
  int l = blockIdx.z;
  int kb = blockIdx.y * 32, nb = blockIdx.x * 32;
  const float* Wl = W + (size_t)l * Dm * Dm;
  bf16* Wtl = Wt + (size_t)l * Dm * Dm;
  int tx = threadIdx.x, ty = threadIdx.y;  // 32 x 8
#pragma unroll
  for (int i = 0; i < 32; i += 8)
    t[ty + i][tx] = Wl[(size_t)(kb + ty + i) * Dm + nb + tx];
  __syncthreads();
#pragma unroll
  for (int i = 0; i < 32; i += 8)
    Wtl[(size_t)(nb + ty + i) * Dm + kb + tx] = (bf16)t[tx][ty + i];
}

// ---------------------------------------------------------------------------
// bf16 MFMA GEMM: C[M][N=768] = A[M][K=768] @ Wt[N][K]^T + bias
// (+gelu if act, +in-register rotary if rot). 128x128 tile, BK=32, 4 waves.
// Double-buffered LDS, counted vmcnt(4), raw s_barrier; XCD block swizzle.
// ---------------------------------------------------------------------------
__global__ __launch_bounds__(256) void gemm_mfma_kernel(
    const bf16* __restrict__ A, const bf16* __restrict__ Wt,
    const float* __restrict__ bias, bf16* __restrict__ C, int act, int rot) {
  const int K = Dm, N = Dm;
  __shared__ bf16 As[2][128 * 32];
  __shared__ bf16 Bs[2][128 * 32];
  const int tid = threadIdx.x;
  const int lane = tid & 63;
  const int wave = tid >> 6;
  const int wr = (wave >> 1) << 6;
  const int wc = (wave & 1) << 6;
  // XCD-bijective swizzle: nwg = 6*256 = 1536 = 8 XCDs * 192; 192 % 6 == 0,
  // so each XCD gets 32 complete A-bands (6 consecutive logical tiles each).
  const int hw = blockIdx.y * gridDim.x + blockIdx.x;
  const int lt = (hw & 7) * 192 + (hw >> 3);
  const int n0 = (lt % 6) << 7;
  const int m0 = (lt / 6) << 7;
  const int c0 = tid, c1 = tid + 256;
  const bf16* a0 = A + (size_t)(m0 + (c0 >> 2)) * K + ((c0 & 3) << 3);
  const bf16* a1 = A + (size_t)(m0 + (c1 >> 2)) * K + ((c1 & 3) << 3);
  const bf16* b0 = Wt + (size_t)(n0 + (c0 >> 2)) * K + ((c0 & 3) << 3);
  const bf16* b1 = Wt + (size_t)(n0 + (c1 >> 2)) * K + ((c1 & 3) << 3);

  const int la = lane & 15, qd = lane >> 4;
  const int aoff = (wr + la) * 32 + qd * 8;
  const int boff = (wc + la) * 32 + qd * 8;

  f32x4 acc[4][4] = {};

#define STAGE(buf, k0)                                                        \
  do {                                                                        \
    __builtin_amdgcn_global_load_lds(AS1(a0 + (k0)), AS3(&As[buf][c0 * 8]),   \
                                     16, 0, 0);                               \
    __builtin_amdgcn_global_load_lds(AS1(a1 + (k0)), AS3(&As[buf][c1 * 8]),   \
                                     16, 0, 0);                               \
    __builtin_amdgcn_global_load_lds(AS1(b0 + (k0)), AS3(&Bs[buf][c0 * 8]),   \
                                     16, 0, 0);                               \
    __builtin_amdgcn_global_load_lds(AS1(b1 + (k0)), AS3(&Bs[buf][c1 * 8]),   \
                                     16, 0, 0);                               \
  } while (0)

#define COMPUTE(buf)                                                          \
  do {                                                                        \
    bf16x8 af[4], bfr[4];                                                     \
    _Pragma("unroll") for (int i = 0; i < 4; ++i) af[i] =                     \
        *(const bf16x8*)(&As[buf][aoff + i * 512]);                           \
    _Pragma("unroll") for (int j = 0; j < 4; ++j) bfr[j] =                    \
        *(const bf16x8*)(&Bs[buf][boff + j * 512]);                           \
    _Pragma("unroll") for (int i = 0; i < 4; ++i)                             \
        _Pragma("unroll") for (int j = 0; j < 4; ++j) acc[i][j] =             \
            __builtin_amdgcn_mfma_f32_16x16x32_bf16(af[i], bfr[j],            \
                                                    acc[i][j], 0, 0, 0);      \
  } while (0)

  STAGE(0, 0);
  int cur = 0;
  for (int t = 0; t < K / 32 - 1; ++t) {
    STAGE(cur ^ 1, (t + 1) * 32);
    asm volatile("s_waitcnt vmcnt(4)" ::: "memory");
    __builtin_amdgcn_s_barrier();
    __builtin_amdgcn_sched_barrier(0);
    COMPUTE(cur);
    __builtin_amdgcn_s_barrier();
    __builtin_amdgcn_sched_barrier(0);
    cur ^= 1;
  }
  asm volatile("s_waitcnt vmcnt(0)" ::: "memory");
  __builtin_amdgcn_s_barrier();
  __builtin_amdgcn_sched_barrier(0);
  COMPUTE(cur);
#undef STAGE
#undef COMPUTE

  // C/D layout: col = lane&15, row = (lane>>4)*4 + reg
  if (!rot) {
#pragma unroll
    for (int i = 0; i < 4; ++i) {
      int rbase = m0 + wr + i * 16 + qd * 4;
#pragma unroll
      for (int j = 0; j < 4; ++j) {
        int col = n0 + wc + j * 16 + la;
        float bc = bias[col];
#pragma unroll
        for (int r = 0; r < 4; ++r) {
          float v = acc[i][j][r] + bc;
          if (act) v = 0.5f * v * (1.0f + erff(v * 0.70710678118654752f));
          C[(size_t)(rbase + r) * N + col] = (bf16)v;
        }
      }
    }
  } else {
    // Wave's 64-col span == one head (n0+wc is 64-aligned). Rotary pair
    // (d, d+32) lives in acc[i][jj] / acc[i][jj+2] of the SAME lane.
#pragma unroll
    for (int i = 0; i < 4; ++i) {
      int rbase = m0 + wr + i * 16 + qd * 4;
#pragma unroll
      for (int jj = 0; jj < 2; ++jj) {
        int d = jj * 16 + la;  // 0..31 within head
        int col1 = n0 + wc + d;
        int col2 = col1 + 32;
        float b1c = bias[col1], b2c = bias[col2];
        float inv = expf(-(float)d * (9.210340371976184f / 32.0f));
#pragma unroll
        for (int r = 0; r < 4; ++r) {
          int row = rbase + r;
          int l = row & (Lseq - 1);
          float fr = (float)l * inv;
          float s, c;
          sincosf(fr, &s, &c);
          float x1 = acc[i][jj][r] + b1c;
          float x2 = acc[i][jj + 2][r] + b2c;
          C[(size_t)row * N + col1] = (bf16)(x1 * c - x2 * s);
          C[(size_t)row * N + col2] = (bf16)(x2 * c + x1 * s);
        }
      }
    }
  }
}

// ---------------------------------------------------------------------------
// Embedding gather -> Xf fp32 + Xb bf16
// ---------------------------------------------------------------------------
__global__ __launch_bounds__(256) void embed_kernel(
    const int* __restrict__ idx, const float* __restrict__ emb,
    float* __restrict__ Xf, bf16* __restrict__ Xb) {
  int o = blockIdx.x * 256 + threadIdx.x;
  int t = o / Dm, d = o - t * Dm;
  float v = emb[(size_t)idx[t] * Dm + d];
  Xf[o] = v;
  Xb[o] = (bf16)v;
}

// ---------------------------------------------------------------------------
// phi = relu(q @ omega) [* mask] via MFMA. Per head: [NTOK x 64] @ [64 x 32].
// Block = (256-token chunk, h). omegaT staged bf16 in LDS [32 f][72 pad].
// Wave = 64 tokens; K=64 -> 2 mfma k-steps; A-frags read direct from global.
// ---------------------------------------------------------------------------
__global__ __launch_bounds__(256) void phi_mfma_kernel(
    const bf16* __restrict__ qk, const float* __restrict__ omega,
    const int* __restrict__ mask, bf16* __restrict__ ph) {
  __shared__ bf16 omT[32][72];
  int tid = threadIdx.x;
  for (int i = tid; i < HDim * Fdim; i += 256) {
    int d = i >> 5, f = i & 31;
    omT[f][d] = (bf16)omega[i];
  }
  __syncthreads();
  const int h = blockIdx.y;
  const int lane = tid & 63, wave = tid >> 6;
  const int la = lane & 15, qd = lane >> 4;
  const int t0 = blockIdx.x * 256 + wave * 64;
  const bf16* qbase = qk + (size_t)t0 * Dm + h * HDim;

  bf16x8 bfr[2][2];
#pragma unroll
  for (int j = 0; j < 2; ++j)
#pragma unroll
    for (int ks = 0; ks < 2; ++ks)
      bfr[j][ks] = *(const bf16x8*)(&omT[j * 16 + la][ks * 32 + qd * 8]);

  f32x4 acc[4][2] = {};
#pragma unroll
  for (int ks = 0; ks < 2; ++ks) {
    bf16x8 af[4];
#pragma unroll
    for (int i = 0; i < 4; ++i)
      af[i] = *(const bf16x8*)(qbase + (size_t)(i * 16 + la) * Dm + ks * 32 +
                               qd * 8);
#pragma unroll
    for (int i = 0; i < 4; ++i)
#pragma unroll
      for (int j = 0; j < 2; ++j)
        acc[i][j] = __builtin_amdgcn_mfma_f32_16x16x32_bf16(af[i], bfr[j][ks],
                                                            acc[i][j], 0, 0, 0);
  }
  // C/D: col f = j*16+la, row t = t0 + i*16 + qd*4 + r
#pragma unroll
  for (int i = 0; i < 4; ++i) {
#pragma unroll
    for (int r = 0; r < 4; ++r) {
      int row = t0 + i * 16 + qd * 4 + r;
      float mm = mask ? (float)mask[row] : 1.0f;
#pragma unroll
      for (int j = 0; j < 2; ++j) {
        float val = fmaxf(acc[i][j][r], 0.0f) * mm;
        ph[(size_t)row * (Hn * Fdim) + h * Fdim + j * 16 + la] = (bf16)val;
      }
    }
  }
}

// ---------------------------------------------------------------------------
// kvsum split-L, no atomics: grid (Bsz*Hn, NSPLIT). Each thread owns
// (f, d0..d0+7) with fp32 register accum; phk scalar load is a wave
// broadcast, v load is bf16x8. Writes per-split partial slabs.
// ---------------------------------------------------------------------------
__global__ __launch_bounds__(256) void kvsum_kernel(
    const bf16* __restrict__ phk, const bf16* __restrict__ v,
    float* __restrict__ kvp, float* __restrict__ ksump) {
  const int bh = blockIdx.x;
  const int b = bh / Hn, h = bh - b * Hn;
  const int s = blockIdx.y;
  const int tid = threadIdx.x;
  const int f = tid >> 3, d0 = (tid & 7) << 3;
  const int lbeg = s * (Lseq / NSPLIT);
  const bf16* pp =
      phk + (size_t)(b * Lseq + lbeg) * (Hn * Fdim) + h * Fdim + f;
  const bf16* vp = v + (size_t)(b * Lseq + lbeg) * Dm + h * HDim + d0;
  float acc[8] = {};
  float ks = 0.0f;
#pragma unroll 4
  for (int l = 0; l < Lseq / NSPLIT; ++l) {
    float p = (float)pp[(size_t)l * (Hn * Fdim)];
    bf16x8 vv = *(const bf16x8*)(vp + (size_t)l * Dm);
    ks += p;
#pragma unroll
    for (int q = 0; q < 8; ++q) acc[q] = fmaf(p, (float)vv[q], acc[q]);
  }
  // layout [s][bh][f][d]: elem offset f*64 + d0 == tid*8
  float* o = kvp + (size_t)(s * (Bsz * Hn) + bh) * (Fdim * HDim) + tid * 8;
  f32x4 lo = {acc[0], acc[1], acc[2], acc[3]};
  f32x4 hi = {acc[4], acc[5], acc[6], acc[7]};
  *(f32x4*)o = lo;
  *(f32x4*)(o + 4) = hi;
  if ((tid & 7) == 0)
    ksump[(size_t)(s * (Bsz * Hn) + bh) * Fdim + f] = ks;
}

// ---------------------------------------------------------------------------
// Reduce NSPLIT partial slabs -> KV, KSUM. Fully overwrites (no zero-init).
// ---------------------------------------------------------------------------
__global__ __launch_bounds__(256) void kvreduce_kernel(
    const float* __restrict__ kvp, const float* __restrict__ ksump,
    float* __restrict__ kv, float* __restrict__ ksum) {
  const int idx = blockIdx.x * 256 + threadIdx.x;  // < 192*2048
  float a = 0.0f;
#pragma unroll
  for (int s = 0; s < NSPLIT; ++s)
    a += kvp[(size_t)s * (Bsz * Hn * Fdim * HDim) + idx];
  kv[idx] = a;
  if (idx < Bsz * Hn * Fdim) {
    float k2 = 0.0f;
#pragma unroll
    for (int s = 0; s < NSPLIT; ++s)
      k2 += ksump[(size_t)s * (Bsz * Hn * Fdim) + idx];
    ksum[idx] = k2;
  }
}

// ---------------------------------------------------------------------------
// zrecip[t,h] = 1 / (sum_f phq[t,h,f]*ksum[b,h,f] + 1e-6)
// ---------------------------------------------------------------------------
__global__ __launch_bounds__(256) void zden_kernel(
    const bf16* __restrict__ phq, const float* __restrict__ ksum,
    float* __restrict__ zr) {
  int idx = blockIdx.x * 256 + threadIdx.x;  // < NTOK*Hn
  int h = idx % Hn;
  int b = idx / (Lseq * Hn);
  const bf16* pq = phq + (size_t)idx * Fdim;
  const float* ks = ksum + ((size_t)b * Hn + h) * Fdim;
  float acc = 0.0f;
#pragma unroll
  for (int f = 0; f < Fdim; ++f) acc = fmaf((float)pq[f], ks[f], acc);
  zr[idx] = 1.0f / (acc + 1e-6f);
}

// ---------------------------------------------------------------------------
// Attention combine via MFMA: out[t,h,:] = (phq[t,h,:] @ kv[b,h]) * zr[t,h].
// Block = (256-token chunk, bh). kv -> bf16 LDS [d][f] (stride 40, 2-way ok).
// K=32 == one mfma_f32_16x16x32_bf16. Wave = 64 tokens x 64 d.
// ---------------------------------------------------------------------------
__global__ __launch_bounds__(256) void attn_mfma_kernel(
    const bf16* __restrict__ phq, const float* __restrict__ kv,
    const float* __restrict__ zr, bf16* __restrict__ out) {
  __shared__ bf16 kvb[64 * 40];
  int bh = blockIdx.y;
  int b = bh / Hn, h = bh - b * Hn;
  int tid = threadIdx.x, lane = tid & 63, wave = tid >> 6;
  {  // transpose-load kv[f][d] fp32 -> kvb[d][f] bf16
    int d = tid >> 2, f0 = (tid & 3) << 3;
    const float* src = kv + ((size_t)bh * Fdim + f0) * HDim + d;
    bf16x8 tmp;
#pragma unroll
    for (int q = 0; q < 8; ++q) tmp[q] = (bf16)src[(size_t)q * HDim];
    *(bf16x8*)(kvb + d * 40 + f0) = tmp;
  }
  __syncthreads();
  const int la = lane & 15, qd = lane >> 4;
  const int t0 = b * Lseq + blockIdx.x * 256 + wave * 64;
  bf16x8 bfr[4];
#pragma unroll
  for (int jt = 0; jt < 4; ++jt)
    bfr[jt] = *(const bf16x8*)(kvb + (jt * 16 + la) * 40 + qd * 8);
  bf16x8 af[4];
#pragma unroll
  for (int i = 0; i < 4; ++i)
    af[i] = *(const bf16x8*)(phq +
                             ((size_t)(t0 + i * 16 + la) * Hn + h) * Fdim +
                             qd * 8);
  f32x4 acc[4][4] = {};
#pragma unroll
  for (int i = 0; i < 4; ++i)
#pragma unroll
    for (int jt = 0; jt < 4; ++jt)
      acc[i][jt] = __builtin_amdgcn_mfma_f32_16x16x32_bf16(af[i], bfr[jt],
                                                           acc[i][jt], 0, 0, 0);
#pragma unroll
  for (int i = 0; i < 4; ++i) {
    int rbase = t0 + i * 16 + qd * 4;
#pragma unroll
    for (int r = 0; r < 4; ++r) {
      float z = zr[(size_t)(rbase + r) * Hn + h];
#pragma unroll
      for (int jt = 0; jt < 4; ++jt)
        out[(size_t)(rbase + r) * Dm + h * HDim + jt * 16 + la] =
            (bf16)(acc[i][jt][r] * z);
    }
  }
}

// ---------------------------------------------------------------------------
// Fused residual + LayerNorm: h = Xf + y; writes Xf (fp32) and Xb (bf16).
// Wave shfl reduce; 2 barriers total.
// ---------------------------------------------------------------------------
__global__ __launch_bounds__(256) void ln_residual_kernel(
    const bf16* __restrict__ y, const float* __restrict__ xres,
    const float* __restrict__ g, const float* __restrict__ be,
    float* __restrict__ xf_out, bf16* __restrict__ xb_out) {
  __shared__ float red[8];
  int t = blockIdx.x, tid = threadIdx.x;
  int lane = tid & 63, wave = tid >> 6;
  const bf16* yr = y + (size_t)t * Dm;
  const float* xr = xres + (size_t)t * Dm;
  float v0 = xr[tid] + (float)yr[tid];
  float v1 = xr[tid + 256] + (float)yr[tid + 256];
  float v2 = xr[tid + 512] + (float)yr[tid + 512];
  float s = v0 + v1 + v2;
#pragma unroll
  for (int off = 32; off > 0; off >>= 1) s += __shfl_xor(s, off, 64);
  if (lane == 0) red[wave] = s;
  __syncthreads();
  float mu = (red[0] + red[1] + red[2] + red[3]) * (1.0f / 768.0f);
  float d0 = v0 - mu, d1 = v1 - mu, d2 = v2 - mu;
  float s2 = d0 * d0 + d1 * d1 + d2 * d2;
#pragma unroll
  for (int off = 32; off > 0; off >>= 1) s2 += __shfl_xor(s2, off, 64);
  if (lane == 0) red[4 + wave] = s2;
  __syncthreads();
  float rs =
      rsqrtf((red[4] + red[5] + red[6] + red[7]) * (1.0f / 768.0f) + 1e-5f);
  float o0 = d0 * rs * g[tid] + be[tid];
  float o1 = d1 * rs * g[tid + 256] + be[tid + 256];
  float o2 = d2 * rs * g[tid + 512] + be[tid + 512];
  float* xo = xf_out + (size_t)t * Dm;
  bf16* bo = xb_out + (size_t)t * Dm;
  xo[tid] = o0;
  xo[tid + 256] = o1;
  xo[tid + 512] = o2;
  bo[tid] = (bf16)o0;
  bo[tid + 256] = (bf16)o1;
  bo[tid + 512] = (bf16)o2;
}

// ---------------------------------------------------------------------------
// Final LayerNorm: fp32 in -> fp32 out (d_out). Wave shfl reduce.
// ---------------------------------------------------------------------------
__global__ __launch_bounds__(256) void ln_final_kernel(
    const float* __restrict__ x, const float* __restrict__ g,
    const float* __restrict__ be, float* __restrict__ out) {
  __shared__ float red[8];
  int t = blockIdx.x, tid = threadIdx.x;
  int lane = tid & 63, wave = tid >> 6;
  const float* xr = x + (size_t)t * Dm;
  float v0 = xr[tid], v1 = xr[tid + 256], v2 = xr[tid + 512];
  float s = v0 + v1 + v2;
#pragma unroll
  for (int off = 32; off > 0; off >>= 1) s += __shfl_xor(s, off, 64);
  if (lane == 0) red[wave] = s;
  __syncthreads();
  float mu = (red[0] + red[1] + red[2] + red[3]) * (1.0f / 768.0f);
  float d0 = v0 - mu, d1 = v1 - mu, d2 = v2 - mu;
  float s2 = d0 * d0 + d1 * d1 + d2 * d2;
#pragma unroll
  for (int off = 32; off > 0; off >>= 1) s2 += __shfl_xor(s2, off, 64);
  if (lane == 0) red[4 + wave] = s2;
  __syncthreads();
  float rs =
      rsqrtf((red[4] + red[5] + red[6] + red[7]) * (1.0f / 768.0f) + 1e-5f);
  float* outr = out + (size_t)t * Dm;
  outr[tid] = d0 * rs * g[tid] + be[tid];
  outr[tid + 256] = d1 * rs * g[tid + 256] + be[tid + 256];
  outr[tid + 512] = d2 * rs * g[tid + 512] + be[tid + 512];
}

// ---------------------------------------------------------------------------
extern "C" void kernel_launch(void* const* d_in, const int* in_sizes, int n_in,
                              void* d_out, int out_size, void* d_ws,
                              size_t ws_size, hipStream_t stream) {
  const int* idx = (const int*)d_in[0];
  const int* mask = (const int*)d_in[1];
  const float* tok_emb = (const float*)d_in[2];
  const float* Wq = (const float*)d_in[3];
  const float* bq = (const float*)d_in[4];
  const float* Wk = (const float*)d_in[5];
  const float* bk = (const float*)d_in[6];
  const float* Wv = (const float*)d_in[7];
  const float* bv = (const float*)d_in[8];
  const float* Wo = (const float*)d_in[9];
  const float* bo = (const float*)d_in[10];
  const float* omega = (const float*)d_in[11];
  const float* W1 = (const float*)d_in[12];
  const float* b1 = (const float*)d_in[13];
  const float* W2 = (const float*)d_in[14];
  const float* b2 = (const float*)d_in[15];
  const float* g1 = (const float*)d_in[16];
  const float* be1 = (const float*)d_in[17];
  const float* g2 = (const float*)d_in[18];
  const float* be2 = (const float*)d_in[19];
  const float* gf = (const float*)d_in[20];
  const float* bf = (const float*)d_in[21];

  const size_t TD = (size_t)NTOK * Dm;
  const size_t WSZ = (size_t)NLayers * Dm * Dm;
  bf16* wsb = (bf16*)d_ws;
  bf16* WqT = wsb;
  bf16* WkT = WqT + WSZ;
  bf16* WvT = WkT + WSZ;
  bf16* WoT = WvT + WSZ;
  bf16* W1T = WoT + WSZ;
  bf16* W2T = W1T + WSZ;
  float* Xf = (float*)(wsb + 6 * WSZ);  // fp32 residual stream
  bf16* Ab = (bf16*)(Xf + TD);          // q/k/v -> attn-out -> ffn hidden
  float* KV = (float*)(Ab + TD);
  float* KSUM = KV + (size_t)Bsz * Hn * Fdim * HDim;
  float* ZR = KSUM + (size_t)Bsz * Hn * Fdim;  // zrecip[t,h], 1.5 MB
  // d_out aliasing: [Xb bf16 (TD)][PHQ (TD/2) | PHK (TD/2) -> y-buf (TD)]
  // KVp/KSUMp partials (25.6 MB) alias the Xb region, which is dead between
  // the V-GEMM (last read) and ln_residual (next write).
  bf16* Xb = (bf16*)d_out;
  bf16* PHQ = Xb + TD;
  bf16* PHK = PHQ + (size_t)NTOK * Hn * Fdim;
  bf16* Yb = PHQ;
  float* KVP = (float*)d_out;
  float* KSUMP = KVP + (size_t)NSPLIT * Bsz * Hn * Fdim * HDim;

  dim3 wg(Dm / 32, Dm / 32, NLayers), wb(32, 8);
  wconv_kernel<<<wg, wb, 0, stream>>>(Wq, WqT);
  wconv_kernel<<<wg, wb, 0, stream>>>(Wk, WkT);
  wconv_kernel<<<wg, wb, 0, stream>>>(Wv, WvT);
  wconv_kernel<<<wg, wb, 0, stream>>>(Wo, WoT);
  wconv_kernel<<<wg, wb, 0, stream>>>(W1, W1T);
  wconv_kernel<<<wg, wb, 0, stream>>>(W2, W2T);

  dim3 gg(Dm / 128, NTOK / 128), gb(256);
  dim3 kvg(Bsz * Hn, NSPLIT);
  dim3 ag(Lseq / 256, Bsz * Hn);
  dim3 pg(NTOK / 256, Hn);
  const int elem_grid = (NTOK * Dm) / 256;
  const int zden_grid = (NTOK * Hn) / 256;
  const int kvr_grid = (Bsz * Hn * Fdim * HDim) / 256;

  embed_kernel<<<elem_grid, 256, 0, stream>>>(idx, tok_emb, Xf, Xb);

  for (int i = 0; i < NLayers; ++i) {
    const size_t wo = (size_t)i * Dm * Dm;
    const size_t bo_ = (size_t)i * Dm;
    const float* omi = omega + (size_t)i * HDim * Fdim;

    // Q (rotary fused) -> Ab -> PHQ
    gemm_mfma_kernel<<<gg, gb, 0, stream>>>(Xb, WqT + wo, bq + bo_, Ab, 0, 1);
    phi_mfma_kernel<<<pg, 256, 0, stream>>>(Ab, omi, nullptr, PHQ);
    // K (rotary fused) -> Ab -> PHK (masked)
    gemm_mfma_kernel<<<gg, gb, 0, stream>>>(Xb, WkT + wo, bk + bo_, Ab, 0, 1);
    phi_mfma_kernel<<<pg, 256, 0, stream>>>(Ab, omi, mask, PHK);
    // V -> Ab; kv state (partials over dead Xb); reduce; zden; attn -> Ab
    gemm_mfma_kernel<<<gg, gb, 0, stream>>>(Xb, WvT + wo, bv + bo_, Ab, 0, 0);
    kvsum_kernel<<<kvg, 256, 0, stream>>>(PHK, Ab, KVP, KSUMP);
    kvreduce_kernel<<<kvr_grid, 256, 0, stream>>>(KVP, KSUMP, KV, KSUM);
    zden_kernel<<<zden_grid, 256, 0, stream>>>(PHQ, KSUM, ZR);
    attn_mfma_kernel<<<ag, 256, 0, stream>>>(PHQ, KV, ZR, Ab);
    // y = attn@Wo + bo -> Yb; LN1(Xf + y) -> Xf, Xb
    gemm_mfma_kernel<<<gg, gb, 0, stream>>>(Ab, WoT + wo, bo + bo_, Yb, 0, 0);
    ln_residual_kernel<<<NTOK, 256, 0, stream>>>(Yb, Xf, g1 + bo_, be1 + bo_,
                                                 Xf, Xb);
    // gelu(Xb@W1+b1) -> Ab; y = Ab@W2+b2 -> Yb; LN2(Xf + y) -> Xf, Xb
    gemm_mfma_kernel<<<gg, gb, 0, stream>>>(Xb, W1T + wo, b1 + bo_, Ab, 1, 0);
    gemm_mfma_kernel<<<gg, gb, 0, stream>>>(Ab, W2T + wo, b2 + bo_, Yb, 0, 0);
    ln_residual_kernel<<<NTOK, 256, 0, stream>>>(Yb, Xf, g2 + bo_, be2 + bo_,
                                                 Xf, Xb);
  }
  ln_final_kernel<<<NTOK, 256, 0, stream>>>(Xf, gf, bf, (float*)d_out);
}

// Round 3
// 2559.131 us; speedup vs baseline: 1.4797x; 1.1396x over previous
//
// FineTuneMolFormer — Round 7: GEMM rebuilt as 256x128 tile, BK=64, 8 waves,
// TRIPLE-buffered LDS (144 KB) with counted s_waitcnt vmcnt(6) that never
// drains to 0 in the main loop (T3/T4), per-phase s_barrier + setprio(1)
// around the 16-MFMA cluster (T5), and T2 chunk-XOR LDS swizzle applied
// both-sides (linear global_load_lds dest + pre-swizzled global source +
// XOR'd ds_read). Grid 768 = 8 XCDs * 96 (96%6==0) -> bijective XCD swizzle,
// and exactly 3 full CU-rounds at 1 block/CU. Everything else = Round 6.
// ws: 6 W^T (28.3) + Xf fp32 (100.7) + Ab (50.3) + KV/KSUM/ZR (3.2) ~= 183 MB.
// d_out: [Xb bf16 | KVp/KSUMp partials][PHQ|PHK / y-buf]; final LN writes last.
#include <hip/hip_runtime.h>
#include <math.h>

#define Bsz 16
#define Lseq 2048
#define Dm 768
#define Hn 12
#define HDim 64
#define Fdim 32
#define NLayers 4
#define NTOK (Bsz * Lseq)
#define NSPLIT 16

typedef __bf16 bf16;
typedef bf16 bf16x8 __attribute__((ext_vector_type(8)));
typedef float f32x4 __attribute__((ext_vector_type(4)));

#define AS1(p) ((__attribute__((address_space(1))) void*)(uintptr_t)(p))
#define AS3(p) ((__attribute__((address_space(3))) void*)(p))

// ---------------------------------------------------------------------------
// Weight convert+transpose: W[l][k][n] fp32 -> Wt[l][n][k] bf16. 32x32 tiles.
// ---------------------------------------------------------------------------
__global__ __launch_bounds__(256) void wconv_kernel(const float* __restrict__ W,
                                                    bf16* __restrict__ Wt) {
  __shared__ float t[32][33];
  int l = blockIdx.z;
  int kb = blockIdx.y * 32, nb = blockIdx.x * 32;
  const float* Wl = W + (size_t)l * Dm * Dm;
  bf16* Wtl = Wt + (size_t)l * Dm * Dm;
  int tx = threadIdx.x, ty = threadIdx.y;  // 32 x 8
#pragma unroll
  for (int i = 0; i < 32; i += 8)
    t[ty + i][tx] = Wl[(size_t)(kb + ty + i) * Dm + nb + tx];
  __syncthreads();
#pragma unroll
  for (int i = 0; i < 32; i += 8)
    Wtl[(size_t)(nb + ty + i) * Dm + kb + tx] = (bf16)t[tx][ty + i];
}

// ---------------------------------------------------------------------------
// bf16 MFMA GEMM: C[M][N=768] = A[M][K=768] @ Wt[N][K]^T + bias
// (+gelu if act, +in-register rotary if rot).
// BM=256 BN=128 BK=64, 8 waves (4M x 2N), triple-buffer LDS, 2 phases/K-tile,
// counted vmcnt(6), chunk-XOR swizzle (both-sides), XCD-bijective blockswz.
// ---------------------------------------------------------------------------
__global__ __launch_bounds__(512, 2) void gemm_mfma_kernel(
    const bf16* __restrict__ A, const bf16* __restrict__ Wt,
    const float* __restrict__ bias, bf16* __restrict__ C, int act, int rot) {
  const int K = Dm, N = Dm;
  constexpr int BM = 256, BN = 128, BK = 64, NBUF = 3;
  __shared__ bf16 As[NBUF][BM * BK];  // 96 KB
  __shared__ bf16 Bs[NBUF][BN * BK];  // 48 KB
  const int tid = threadIdx.x;
  const int lane = tid & 63;
  const int wave = tid >> 6;  // 0..7
  const int wm = wave >> 1;   // 0..3 -> M sub-band (64 rows)
  const int wn = wave & 1;    // 0..1 -> N sub-band (64 cols)
  // XCD-bijective swizzle: nwg = 6*128 = 768 = 8 XCDs * 96; 96 % 6 == 0,
  // so each XCD owns 16 complete A-bands (6 consecutive logical tiles).
  const int hw = blockIdx.y * gridDim.x + blockIdx.x;
  const int lt = (hw & 7) * 96 + (hw >> 3);
  const int n0 = (lt % 6) * BN;
  const int m0 = (lt / 6) * BM;

  const int la = lane & 15, qd = lane >> 4;

  // Staging: A = 4 slots/thread, B = 2 slots/thread, 16 B each.
  // LDS dest is LINEAR in slot (global_load_lds: lane-linear dest required);
  // the 16B chunk-permutation c -> c^(row&7) is applied on the GLOBAL source
  // (rule #21: swizzle both-sides-or-neither).
  const bf16* aps[4];
  int alds[4];
#pragma unroll
  for (int r = 0; r < 4; ++r) {
    int s = r * 512 + tid;
    int row = s >> 3, cpos = s & 7;
    aps[r] = A + (size_t)(m0 + row) * K + ((cpos ^ (row & 7)) << 3);
    alds[r] = s * 8;
  }
  const bf16* bps[2];
  int blds[2];
#pragma unroll
  for (int r = 0; r < 2; ++r) {
    int s = r * 512 + tid;
    int row = s >> 3, cpos = s & 7;
    bps[r] = Wt + (size_t)(n0 + row) * K + ((cpos ^ (row & 7)) << 3);
    blds[r] = s * 8;
  }

  // Fragment read bases (elements) + row&7 for the read-side XOR.
  int abase[4], am7[4];
#pragma unroll
  for (int i = 0; i < 4; ++i) {
    int row = wm * 64 + i * 16 + la;
    abase[i] = row * BK;
    am7[i] = row & 7;
  }
  int bbase[4], bm7[4];
#pragma unroll
  for (int j = 0; j < 4; ++j) {
    int row = wn * 64 + j * 16 + la;
    bbase[j] = row * BK;
    bm7[j] = row & 7;
  }

  f32x4 acc[4][4] = {};

#define STAGE_P0(bufx, k0)                                                   \
  do {                                                                       \
    __builtin_amdgcn_global_load_lds(AS1(aps[0] + (k0)),                     \
                                     AS3(&As[bufx][alds[0]]), 16, 0, 0);     \
    __builtin_amdgcn_global_load_lds(AS1(aps[1] + (k0)),                     \
                                     AS3(&As[bufx][alds[1]]), 16, 0, 0);     \
    __builtin_amdgcn_global_load_lds(AS1(aps[2] + (k0)),                     \
                                     AS3(&As[bufx][alds[2]]), 16, 0, 0);     \
  } while (0)
#define STAGE_P1(bufx, k0)                                                   \
  do {                                                                       \
    __builtin_amdgcn_global_load_lds(AS1(aps[3] + (k0)),                     \
                                     AS3(&As[bufx][alds[3]]), 16, 0, 0);     \
    __builtin_amdgcn_global_load_lds(AS1(bps[0] + (k0)),                     \
                                     AS3(&Bs[bufx][blds[0]]), 16, 0, 0);     \
    __builtin_amdgcn_global_load_lds(AS1(bps[1] + (k0)),                     \
                                     AS3(&Bs[bufx][blds[1]]), 16, 0, 0);     \
  } while (0)

  // One phase = 8 ds_read_b128 + barrier + 16-MFMA cluster (one k32 slice).
#define PHASE(bufx, ks)                                                      \
  do {                                                                       \
    bf16x8 af[4], bfr[4];                                                    \
    _Pragma("unroll") for (int i = 0; i < 4; ++i) af[i] =                    \
        *(const bf16x8*)(&As[bufx][abase[i] +                                \
                                   ((((ks)*4 + qd) ^ am7[i]) << 3)]);        \
    _Pragma("unroll") for (int j = 0; j < 4; ++j) bfr[j] =                   \
        *(const bf16x8*)(&Bs[bufx][bbase[j] +                                \
                                   ((((ks)*4 + qd) ^ bm7[j]) << 3)]);        \
    __builtin_amdgcn_s_barrier();                                            \
    __builtin_amdgcn_sched_barrier(0);                                       \
    __builtin_amdgcn_s_setprio(1);                                           \
    _Pragma("unroll") for (int i = 0; i < 4; ++i)                            \
        _Pragma("unroll") for (int j = 0; j < 4; ++j) acc[i][j] =            \
            __builtin_amdgcn_mfma_f32_16x16x32_bf16(af[i], bfr[j],           \
                                                    acc[i][j], 0, 0, 0);     \
    __builtin_amdgcn_s_setprio(0);                                           \
  } while (0)

  // Prologue: stage tiles 0 and 1 (6 loads each); wait tile0 (vmcnt(6):
  // tile1's 6 loads stay in flight).
  STAGE_P0(0, 0);
  STAGE_P1(0, 0);
  STAGE_P0(1, BK);
  STAGE_P1(1, BK);
  asm volatile("s_waitcnt vmcnt(6)" ::: "memory");
  __builtin_amdgcn_s_barrier();
  __builtin_amdgcn_sched_barrier(0);

  const int NT = K / BK;  // 12
  int bufc = 0, bufn = 2;
  for (int t = 0; t < NT; ++t) {
    const bool st = (t + 2) < NT;
    if (st) STAGE_P0(bufn, (t + 2) * BK);
    PHASE(bufc, 0);
    if (st) STAGE_P1(bufn, (t + 2) * BK);
    PHASE(bufc, 1);
    if (t < NT - 1) {
      // Ensure tile t+1 resident; keep tile t+2's 6 loads in flight.
      if (st)
        asm volatile("s_waitcnt vmcnt(6)" ::: "memory");
      else
        asm volatile("s_waitcnt vmcnt(0)" ::: "memory");
      __builtin_amdgcn_s_barrier();
      __builtin_amdgcn_sched_barrier(0);
    }
    bufc = (bufc + 1 == NBUF) ? 0 : bufc + 1;
    bufn = (bufn + 1 == NBUF) ? 0 : bufn + 1;
  }
#undef STAGE_P0
#undef STAGE_P1
#undef PHASE

  // C/D layout: col = lane&15, row = (lane>>4)*4 + reg
  if (!rot) {
#pragma unroll
    for (int i = 0; i < 4; ++i) {
      int rbase = m0 + wm * 64 + i * 16 + qd * 4;
#pragma unroll
      for (int j = 0; j < 4; ++j) {
        int col = n0 + wn * 64 + j * 16 + la;
        float bc = bias[col];
#pragma unroll
        for (int r = 0; r < 4; ++r) {
          float v = acc[i][j][r] + bc;
          if (act) v = 0.5f * v * (1.0f + erff(v * 0.70710678118654752f));
          C[(size_t)(rbase + r) * N + col] = (bf16)v;
        }
      }
    }
  } else {
    // Wave's 64-col span == one head (n0 + wn*64 is 64-aligned). Rotary pair
    // (d, d+32) lives in acc[i][jj] / acc[i][jj+2] of the SAME lane.
#pragma unroll
    for (int i = 0; i < 4; ++i) {
      int rbase = m0 + wm * 64 + i * 16 + qd * 4;
#pragma unroll
      for (int jj = 0; jj < 2; ++jj) {
        int d = jj * 16 + la;  // 0..31 within head
        int col1 = n0 + wn * 64 + d;
        int col2 = col1 + 32;
        float b1c = bias[col1], b2c = bias[col2];
        float inv = expf(-(float)d * (9.210340371976184f / 32.0f));
#pragma unroll
        for (int r = 0; r < 4; ++r) {
          int row = rbase + r;
          int l = row & (Lseq - 1);
          float fr = (float)l * inv;
          float s, c;
          sincosf(fr, &s, &c);
          float x1 = acc[i][jj][r] + b1c;
          float x2 = acc[i][jj + 2][r] + b2c;
          C[(size_t)row * N + col1] = (bf16)(x1 * c - x2 * s);
          C[(size_t)row * N + col2] = (bf16)(x2 * c + x1 * s);
        }
      }
    }
  }
}

// ---------------------------------------------------------------------------
// Embedding gather -> Xf fp32 + Xb bf16
// ---------------------------------------------------------------------------
__global__ __launch_bounds__(256) void embed_kernel(
    const int* __restrict__ idx, const float* __restrict__ emb,
    float* __restrict__ Xf, bf16* __restrict__ Xb) {
  int o = blockIdx.x * 256 + threadIdx.x;
  int t = o / Dm, d = o - t * Dm;
  float v = emb[(size_t)idx[t] * Dm + d];
  Xf[o] = v;
  Xb[o] = (bf16)v;
}

// ---------------------------------------------------------------------------
// phi = relu(q @ omega) [* mask] via MFMA. Per head: [NTOK x 64] @ [64 x 32].
// Block = (256-token chunk, h). omegaT staged bf16 in LDS [32 f][72 pad].
// Wave = 64 tokens; K=64 -> 2 mfma k-steps; A-frags read direct from global.
// ---------------------------------------------------------------------------
__global__ __launch_bounds__(256) void phi_mfma_kernel(
    const bf16* __restrict__ qk, const float* __restrict__ omega,
    const int* __restrict__ mask, bf16* __restrict__ ph) {
  __shared__ bf16 omT[32][72];
  int tid = threadIdx.x;
  for (int i = tid; i < HDim * Fdim; i += 256) {
    int d = i >> 5, f = i & 31;
    omT[f][d] = (bf16)omega[i];
  }
  __syncthreads();
  const int h = blockIdx.y;
  const int lane = tid & 63, wave = tid >> 6;
  const int la = lane & 15, qd = lane >> 4;
  const int t0 = blockIdx.x * 256 + wave * 64;
  const bf16* qbase = qk + (size_t)t0 * Dm + h * HDim;

  bf16x8 bfr[2][2];
#pragma unroll
  for (int j = 0; j < 2; ++j)
#pragma unroll
    for (int ks = 0; ks < 2; ++ks)
      bfr[j][ks] = *(const bf16x8*)(&omT[j * 16 + la][ks * 32 + qd * 8]);

  f32x4 acc[4][2] = {};
#pragma unroll
  for (int ks = 0; ks < 2; ++ks) {
    bf16x8 af[4];
#pragma unroll
    for (int i = 0; i < 4; ++i)
      af[i] = *(const bf16x8*)(qbase + (size_t)(i * 16 + la) * Dm + ks * 32 +
                               qd * 8);
#pragma unroll
    for (int i = 0; i < 4; ++i)
#pragma unroll
      for (int j = 0; j < 2; ++j)
        acc[i][j] = __builtin_amdgcn_mfma_f32_16x16x32_bf16(af[i], bfr[j][ks],
                                                            acc[i][j], 0, 0, 0);
  }
  // C/D: col f = j*16+la, row t = t0 + i*16 + qd*4 + r
#pragma unroll
  for (int i = 0; i < 4; ++i) {
#pragma unroll
    for (int r = 0; r < 4; ++r) {
      int row = t0 + i * 16 + qd * 4 + r;
      float mm = mask ? (float)mask[row] : 1.0f;
#pragma unroll
      for (int j = 0; j < 2; ++j) {
        float val = fmaxf(acc[i][j][r], 0.0f) * mm;
        ph[(size_t)row * (Hn * Fdim) + h * Fdim + j * 16 + la] = (bf16)val;
      }
    }
  }
}

// ---------------------------------------------------------------------------
// kvsum split-L, no atomics: grid (Bsz*Hn, NSPLIT). Each thread owns
// (f, d0..d0+7) with fp32 register accum; phk scalar load is a wave
// broadcast, v load is bf16x8. Writes per-split partial slabs.
// ---------------------------------------------------------------------------
__global__ __launch_bounds__(256) void kvsum_kernel(
    const bf16* __restrict__ phk, const bf16* __restrict__ v,
    float* __restrict__ kvp, float* __restrict__ ksump) {
  const int bh = blockIdx.x;
  const int b = bh / Hn, h = bh - b * Hn;
  const int s = blockIdx.y;
  const int tid = threadIdx.x;
  const int f = tid >> 3, d0 = (tid & 7) << 3;
  const int lbeg = s * (Lseq / NSPLIT);
  const bf16* pp =
      phk + (size_t)(b * Lseq + lbeg) * (Hn * Fdim) + h * Fdim + f;
  const bf16* vp = v + (size_t)(b * Lseq + lbeg) * Dm + h * HDim + d0;
  float acc[8] = {};
  float ks = 0.0f;
#pragma unroll 4
  for (int l = 0; l < Lseq / NSPLIT; ++l) {
    float p = (float)pp[(size_t)l * (Hn * Fdim)];
    bf16x8 vv = *(const bf16x8*)(vp + (size_t)l * Dm);
    ks += p;
#pragma unroll
    for (int q = 0; q < 8; ++q) acc[q] = fmaf(p, (float)vv[q], acc[q]);
  }
  // layout [s][bh][f][d]: elem offset f*64 + d0 == tid*8
  float* o = kvp + (size_t)(s * (Bsz * Hn) + bh) * (Fdim * HDim) + tid * 8;
  f32x4 lo = {acc[0], acc[1], acc[2], acc[3]};
  f32x4 hi = {acc[4], acc[5], acc[6], acc[7]};
  *(f32x4*)o = lo;
  *(f32x4*)(o + 4) = hi;
  if ((tid & 7) == 0)
    ksump[(size_t)(s * (Bsz * Hn) + bh) * Fdim + f] = ks;
}

// ---------------------------------------------------------------------------
// Reduce NSPLIT partial slabs -> KV, KSUM. Fully overwrites (no zero-init).
// ---------------------------------------------------------------------------
__global__ __launch_bounds__(256) void kvreduce_kernel(
    const float* __restrict__ kvp, const float* __restrict__ ksump,
    float* __restrict__ kv, float* __restrict__ ksum) {
  const int idx = blockIdx.x * 256 + threadIdx.x;  // < 192*2048
  float a = 0.0f;
#pragma unroll
  for (int s = 0; s < NSPLIT; ++s)
    a += kvp[(size_t)s * (Bsz * Hn * Fdim * HDim) + idx];
  kv[idx] = a;
  if (idx < Bsz * Hn * Fdim) {
    float k2 = 0.0f;
#pragma unroll
    for (int s = 0; s < NSPLIT; ++s)
      k2 += ksump[(size_t)s * (Bsz * Hn * Fdim) + idx];
    ksum[idx] = k2;
  }
}

// ---------------------------------------------------------------------------
// zrecip[t,h] = 1 / (sum_f phq[t,h,f]*ksum[b,h,f] + 1e-6)
// ---------------------------------------------------------------------------
__global__ __launch_bounds__(256) void zden_kernel(
    const bf16* __restrict__ phq, const float* __restrict__ ksum,
    float* __restrict__ zr) {
  int idx = blockIdx.x * 256 + threadIdx.x;  // < NTOK*Hn
  int h = idx % Hn;
  int b = idx / (Lseq * Hn);
  const bf16* pq = phq + (size_t)idx * Fdim;
  const float* ks = ksum + ((size_t)b * Hn + h) * Fdim;
  float acc = 0.0f;
#pragma unroll
  for (int f = 0; f < Fdim; ++f) acc = fmaf((float)pq[f], ks[f], acc);
  zr[idx] = 1.0f / (acc + 1e-6f);
}

// ---------------------------------------------------------------------------
// Attention combine via MFMA: out[t,h,:] = (phq[t,h,:] @ kv[b,h]) * zr[t,h].
// Block = (256-token chunk, bh). kv -> bf16 LDS [d][f] (stride 40, 2-way ok).
// K=32 == one mfma_f32_16x16x32_bf16. Wave = 64 tokens x 64 d.
// ---------------------------------------------------------------------------
__global__ __launch_bounds__(256) void attn_mfma_kernel(
    const bf16* __restrict__ phq, const float* __restrict__ kv,
    const float* __restrict__ zr, bf16* __restrict__ out) {
  __shared__ bf16 kvb[64 * 40];
  int bh = blockIdx.y;
  int b = bh / Hn, h = bh - b * Hn;
  int tid = threadIdx.x, lane = tid & 63, wave = tid >> 6;
  {  // transpose-load kv[f][d] fp32 -> kvb[d][f] bf16
    int d = tid >> 2, f0 = (tid & 3) << 3;
    const float* src = kv + ((size_t)bh * Fdim + f0) * HDim + d;
    bf16x8 tmp;
#pragma unroll
    for (int q = 0; q < 8; ++q) tmp[q] = (bf16)src[(size_t)q * HDim];
    *(bf16x8*)(kvb + d * 40 + f0) = tmp;
  }
  __syncthreads();
  const int la = lane & 15, qd = lane >> 4;
  const int t0 = b * Lseq + blockIdx.x * 256 + wave * 64;
  bf16x8 bfr[4];
#pragma unroll
  for (int jt = 0; jt < 4; ++jt)
    bfr[jt] = *(const bf16x8*)(kvb + (jt * 16 + la) * 40 + qd * 8);
  bf16x8 af[4];
#pragma unroll
  for (int i = 0; i < 4; ++i)
    af[i] = *(const bf16x8*)(phq +
                             ((size_t)(t0 + i * 16 + la) * Hn + h) * Fdim +
                             qd * 8);
  f32x4 acc[4][4] = {};
#pragma unroll
  for (int i = 0; i < 4; ++i)
#pragma unroll
    for (int jt = 0; jt < 4; ++jt)
      acc[i][jt] = __builtin_amdgcn_mfma_f32_16x16x32_bf16(af[i], bfr[jt],
                                                           acc[i][jt], 0, 0, 0);
#pragma unroll
  for (int i = 0; i < 4; ++i) {
    int rbase = t0 + i * 16 + qd * 4;
#pragma unroll
    for (int r = 0; r < 4; ++r) {
      float z = zr[(size_t)(rbase + r) * Hn + h];
#pragma unroll
      for (int jt = 0; jt < 4; ++jt)
        out[(size_t)(rbase + r) * Dm + h * HDim + jt * 16 + la] =
            (bf16)(acc[i][jt][r] * z);
    }
  }
}

// ---------------------------------------------------------------------------
// Fused residual + LayerNorm: h = Xf + y; writes Xf (fp32) and Xb (bf16).
// Wave shfl reduce; 2 barriers total.
// ---------------------------------------------------------------------------
__global__ __launch_bounds__(256) void ln_residual_kernel(
    const bf16* __restrict__ y, const float* __restrict__ xres,
    const float* __restrict__ g, const float* __restrict__ be,
    float* __restrict__ xf_out, bf16* __restrict__ xb_out) {
  __shared__ float red[8];
  int t = blockIdx.x, tid = threadIdx.x;
  int lane = tid & 63, wave = tid >> 6;
  const bf16* yr = y + (size_t)t * Dm;
  const float* xr = xres + (size_t)t * Dm;
  float v0 = xr[tid] + (float)yr[tid];
  float v1 = xr[tid + 256] + (float)yr[tid + 256];
  float v2 = xr[tid + 512] + (float)yr[tid + 512];
  float s = v0 + v1 + v2;
#pragma unroll
  for (int off = 32; off > 0; off >>= 1) s += __shfl_xor(s, off, 64);
  if (lane == 0) red[wave] = s;
  __syncthreads();
  float mu = (red[0] + red[1] + red[2] + red[3]) * (1.0f / 768.0f);
  float d0 = v0 - mu, d1 = v1 - mu, d2 = v2 - mu;
  float s2 = d0 * d0 + d1 * d1 + d2 * d2;
#pragma unroll
  for (int off = 32; off > 0; off >>= 1) s2 += __shfl_xor(s2, off, 64);
  if (lane == 0) red[4 + wave] = s2;
  __syncthreads();
  float rs =
      rsqrtf((red[4] + red[5] + red[6] + red[7]) * (1.0f / 768.0f) + 1e-5f);
  float o0 = d0 * rs * g[tid] + be[tid];
  float o1 = d1 * rs * g[tid + 256] + be[tid + 256];
  float o2 = d2 * rs * g[tid + 512] + be[tid + 512];
  float* xo = xf_out + (size_t)t * Dm;
  bf16* bo = xb_out + (size_t)t * Dm;
  xo[tid] = o0;
  xo[tid + 256] = o1;
  xo[tid + 512] = o2;
  bo[tid] = (bf16)o0;
  bo[tid + 256] = (bf16)o1;
  bo[tid + 512] = (bf16)o2;
}

// ---------------------------------------------------------------------------
// Final LayerNorm: fp32 in -> fp32 out (d_out). Wave shfl reduce.
// ---------------------------------------------------------------------------
__global__ __launch_bounds__(256) void ln_final_kernel(
    const float* __restrict__ x, const float* __restrict__ g,
    const float* __restrict__ be, float* __restrict__ out) {
  __shared__ float red[8];
  int t = blockIdx.x, tid = threadIdx.x;
  int lane = tid & 63, wave = tid >> 6;
  const float* xr = x + (size_t)t * Dm;
  float v0 = xr[tid], v1 = xr[tid + 256], v2 = xr[tid + 512];
  float s = v0 + v1 + v2;
#pragma unroll
  for (int off = 32; off > 0; off >>= 1) s += __shfl_xor(s, off, 64);
  if (lane == 0) red[wave] = s;
  __syncthreads();
  float mu = (red[0] + red[1] + red[2] + red[3]) * (1.0f / 768.0f);
  float d0 = v0 - mu, d1 = v1 - mu, d2 = v2 - mu;
  float s2 = d0 * d0 + d1 * d1 + d2 * d2;
#pragma unroll
  for (int off = 32; off > 0; off >>= 1) s2 += __shfl_xor(s2, off, 64);
  if (lane == 0) red[4 + wave] = s2;
  __syncthreads();
  float rs =
      rsqrtf((red[4] + red[5] + red[6] + red[7]) * (1.0f / 768.0f) + 1e-5f);
  float* outr = out + (size_t)t * Dm;
  outr[tid] = d0 * rs * g[tid] + be[tid];
  outr[tid + 256] = d1 * rs * g[tid + 256] + be[tid + 256];
  outr[tid + 512] = d2 * rs * g[tid + 512] + be[tid + 512];
}

// ---------------------------------------------------------------------------
extern "C" void kernel_launch(void* const* d_in, const int* in_sizes, int n_in,
                              void* d_out, int out_size, void* d_ws,
                              size_t ws_size, hipStream_t stream) {
  const int* idx = (const int*)d_in[0];
  const int* mask = (const int*)d_in[1];
  const float* tok_emb = (const float*)d_in[2];
  const float* Wq = (const float*)d_in[3];
  const float* bq = (const float*)d_in[4];
  const float* Wk = (const float*)d_in[5];
  const float* bk = (const float*)d_in[6];
  const float* Wv = (const float*)d_in[7];
  const float* bv = (const float*)d_in[8];
  const float* Wo = (const float*)d_in[9];
  const float* bo = (const float*)d_in[10];
  const float* omega = (const float*)d_in[11];
  const float* W1 = (const float*)d_in[12];
  const float* b1 = (const float*)d_in[13];
  const float* W2 = (const float*)d_in[14];
  const float* b2 = (const float*)d_in[15];
  const float* g1 = (const float*)d_in[16];
  const float* be1 = (const float*)d_in[17];
  const float* g2 = (const float*)d_in[18];
  const float* be2 = (const float*)d_in[19];
  const float* gf = (const float*)d_in[20];
  const float* bf = (const float*)d_in[21];

  const size_t TD = (size_t)NTOK * Dm;
  const size_t WSZ = (size_t)NLayers * Dm * Dm;
  bf16* wsb = (bf16*)d_ws;
  bf16* WqT = wsb;
  bf16* WkT = WqT + WSZ;
  bf16* WvT = WkT + WSZ;
  bf16* WoT = WvT + WSZ;
  bf16* W1T = WoT + WSZ;
  bf16* W2T = W1T + WSZ;
  float* Xf = (float*)(wsb + 6 * WSZ);  // fp32 residual stream
  bf16* Ab = (bf16*)(Xf + TD);          // q/k/v -> attn-out -> ffn hidden
  float* KV = (float*)(Ab + TD);
  float* KSUM = KV + (size_t)Bsz * Hn * Fdim * HDim;
  float* ZR = KSUM + (size_t)Bsz * Hn * Fdim;  // zrecip[t,h], 1.5 MB
  // d_out aliasing: [Xb bf16 (TD)][PHQ (TD/2) | PHK (TD/2) -> y-buf (TD)]
  // KVp/KSUMp partials (25.6 MB) alias the Xb region, which is dead between
  // the V-GEMM (last read) and ln_residual (next write).
  bf16* Xb = (bf16*)d_out;
  bf16* PHQ = Xb + TD;
  bf16* PHK = PHQ + (size_t)NTOK * Hn * Fdim;
  bf16* Yb = PHQ;
  float* KVP = (float*)d_out;
  float* KSUMP = KVP + (size_t)NSPLIT * Bsz * Hn * Fdim * HDim;

  dim3 wg(Dm / 32, Dm / 32, NLayers), wb(32, 8);
  wconv_kernel<<<wg, wb, 0, stream>>>(Wq, WqT);
  wconv_kernel<<<wg, wb, 0, stream>>>(Wk, WkT);
  wconv_kernel<<<wg, wb, 0, stream>>>(Wv, WvT);
  wconv_kernel<<<wg, wb, 0, stream>>>(Wo, WoT);
  wconv_kernel<<<wg, wb, 0, stream>>>(W1, W1T);
  wconv_kernel<<<wg, wb, 0, stream>>>(W2, W2T);

  dim3 gg(Dm / 128, NTOK / 256), gb(512);  // 768 blocks, 512 threads
  dim3 kvg(Bsz * Hn, NSPLIT);
  dim3 ag(Lseq / 256, Bsz * Hn);
  dim3 pg(NTOK / 256, Hn);
  const int elem_grid = (NTOK * Dm) / 256;
  const int zden_grid = (NTOK * Hn) / 256;
  const int kvr_grid = (Bsz * Hn * Fdim * HDim) / 256;

  embed_kernel<<<elem_grid, 256, 0, stream>>>(idx, tok_emb, Xf, Xb);

  for (int i = 0; i < NLayers; ++i) {
    const size_t wo = (size_t)i * Dm * Dm;
    const size_t bo_ = (size_t)i * Dm;
    const float* omi = omega + (size_t)i * HDim * Fdim;

    // Q (rotary fused) -> Ab -> PHQ
    gemm_mfma_kernel<<<gg, gb, 0, stream>>>(Xb, WqT + wo, bq + bo_, Ab, 0, 1);
    phi_mfma_kernel<<<pg, 256, 0, stream>>>(Ab, omi, nullptr, PHQ);
    // K (rotary fused) -> Ab -> PHK (masked)
    gemm_mfma_kernel<<<gg, gb, 0, stream>>>(Xb, WkT + wo, bk + bo_, Ab, 0, 1);
    phi_mfma_kernel<<<pg, 256, 0, stream>>>(Ab, omi, mask, PHK);
    // V -> Ab; kv state (partials over dead Xb); reduce; zden; attn -> Ab
    gemm_mfma_kernel<<<gg, gb, 0, stream>>>(Xb, WvT + wo, bv + bo_, Ab, 0, 0);
    kvsum_kernel<<<kvg, 256, 0, stream>>>(PHK, Ab, KVP, KSUMP);
    kvreduce_kernel<<<kvr_grid, 256, 0, stream>>>(KVP, KSUMP, KV, KSUM);
    zden_kernel<<<zden_grid, 256, 0, stream>>>(PHQ, KSUM, ZR);
    attn_mfma_kernel<<<ag, 256, 0, stream>>>(PHQ, KV, ZR, Ab);
    // y = attn@Wo + bo -> Yb; LN1(Xf + y) -> Xf, Xb
    gemm_mfma_kernel<<<gg, gb, 0, stream>>>(Ab, WoT + wo, bo + bo_, Yb, 0, 0);
    ln_residual_kernel<<<NTOK, 256, 0, stream>>>(Yb, Xf, g1 + bo_, be1 + bo_,
                                                 Xf, Xb);
    // gelu(Xb@W1+b1) -> Ab; y = Ab@W2+b2 -> Yb; LN2(Xf + y) -> Xf, Xb
    gemm_mfma_kernel<<<gg, gb, 0, stream>>>(Xb, W1T + wo, b1 + bo_, Ab, 1, 0);
    gemm_mfma_kernel<<<gg, gb, 0, stream>>>(Ab, W2T + wo, b2 + bo_, Yb, 0, 0);
    ln_residual_kernel<<<NTOK, 256, 0, stream>>>(Yb, Xf, g2 + bo_, be2 + bo_,
                                                 Xf, Xb);
  }
  ln_final_kernel<<<NTOK, 256, 0, stream>>>(Xf, gf, bf, (float*)d_out);
}